// Round 2
// baseline (176.578 us; speedup 1.0000x reference)
//
#include <hip/hip_runtime.h>
#include <hip/hip_bf16.h>
#include <stdint.h>

typedef __hip_bfloat16 bf16_t;
typedef __attribute__((ext_vector_type(8))) __bf16 bf16x8;
typedef __attribute__((ext_vector_type(4))) float floatx4;

#define BM 128
#define BN 128
#define BK 64

// async 16B global->LDS (wave-uniform base + lane*16; our layouts satisfy this)
__device__ inline void async_load16(const void* g, void* l) {
  __builtin_amdgcn_global_load_lds(
      (const __attribute__((address_space(1))) unsigned int*)g,
      (__attribute__((address_space(3))) unsigned int*)l,
      16, 0, 0);
}

__device__ inline void unpack8_bf16(float* dst, uint4 u) {
  const unsigned w[4] = {u.x, u.y, u.z, u.w};
#pragma unroll
  for (int p = 0; p < 4; ++p) {
    dst[2 * p]     = __uint_as_float(w[p] << 16);
    dst[2 * p + 1] = __uint_as_float(w[p] & 0xffff0000u);
  }
}

__device__ inline unsigned short bf16_bits(float f) {
  bf16_t b = __float2bfloat16(f);
  return *(const unsigned short*)&b;
}

// fp32 -> bf16, 4 elements/thread, exact sizes (n % 1024 == 0)
__global__ void cvt_one(const float* __restrict__ src, bf16_t* __restrict__ dst) {
  const int i = (blockIdx.x * 256 + threadIdx.x) * 4;
  float4 f = *(const float4*)(src + i);
  union { unsigned short u[4]; uint2 v; } p;
  p.u[0] = bf16_bits(f.x); p.u[1] = bf16_bits(f.y);
  p.u[2] = bf16_bits(f.z); p.u[3] = bf16_bits(f.w);
  *(uint2*)(dst + i) = p.v;
}

// 4 weight matrices (1024x1024 each) in one launch, selected by blockIdx.y
__global__ void cvt_w4(const float* __restrict__ s0, const float* __restrict__ s1,
                       const float* __restrict__ s2, const float* __restrict__ s3,
                       bf16_t* __restrict__ d0, bf16_t* __restrict__ d1,
                       bf16_t* __restrict__ d2, bf16_t* __restrict__ d3) {
  const float* s; bf16_t* d;
  switch (blockIdx.y) {
    case 0: s = s0; d = d0; break;
    case 1: s = s1; d = d1; break;
    case 2: s = s2; d = d2; break;
    default: s = s3; d = d3; break;
  }
  const int i = (blockIdx.x * 256 + threadIdx.x) * 4;
  float4 f = *(const float4*)(s + i);
  union { unsigned short u[4]; uint2 v; } p;
  p.u[0] = bf16_bits(f.x); p.u[1] = bf16_bits(f.y);
  p.u[2] = bf16_bits(f.z); p.u[3] = bf16_bits(f.w);
  *(uint2*)(d + i) = p.v;
}

// C[M,N] = A[M,K] * B[N,K]^T ; A,B bf16 row-major; fp32 accum; OutT out.
// B matrix chosen per 1024-column group of C from {B0,B1,B2} (QKV fusion).
// XOR swizzle: LDS granule slot g of row r holds global granule g^(r&7).
template <typename OutT>
__global__ __launch_bounds__(256, 2)
void gemm_nt(const bf16_t* __restrict__ A, int lda,
             const bf16_t* __restrict__ B0, const bf16_t* __restrict__ B1,
             const bf16_t* __restrict__ B2,
             OutT* __restrict__ C, int ldc, int Kdim)
{
  __shared__ alignas(16) __bf16 As[BM * BK];
  __shared__ alignas(16) __bf16 Bs[BN * BK];

  const int t = threadIdx.x;
  const int lane = t & 63;
  const int wave = t >> 6;
  const int wm = wave >> 1;   // 0..1
  const int wn = wave & 1;    // 0..1

  const int m0 = blockIdx.x * BM;
  const int nblk = blockIdx.y * BN;
  const int mat = nblk >> 10;
  const bf16_t* __restrict__ B = (mat == 0) ? B0 : ((mat == 1) ? B1 : B2);
  const int n0 = nblk & 1023;

  floatx4 acc[4][4];
#pragma unroll
  for (int i = 0; i < 4; ++i)
#pragma unroll
    for (int j = 0; j < 4; ++j)
      acc[i][j] = (floatx4){0.f, 0.f, 0.f, 0.f};

  const int srow = t >> 3;   // staging row within 32-row chunk
  const int sgs = t & 7;     // LDS granule slot

  for (int k0 = 0; k0 < Kdim; k0 += BK) {
#pragma unroll
    for (int r4 = 0; r4 < 4; ++r4) {
      const int row = r4 * 32 + srow;
      const int gsrc = sgs ^ (row & 7);
      async_load16(A + (size_t)(m0 + row) * lda + k0 + gsrc * 8,
                   &As[row * BK + sgs * 8]);
      async_load16(B + (size_t)(n0 + row) * Kdim + k0 + gsrc * 8,
                   &Bs[row * BK + sgs * 8]);
    }
    __syncthreads();
#pragma unroll
    for (int ks = 0; ks < 2; ++ks) {
      bf16x8 af[4], bfv[4];
#pragma unroll
      for (int i = 0; i < 4; ++i) {
        const int row = wm * 64 + i * 16 + (lane & 15);
        const int g = ks * 4 + (lane >> 4);
        af[i] = *(const bf16x8*)&As[row * BK + (g ^ (row & 7)) * 8];
      }
#pragma unroll
      for (int j = 0; j < 4; ++j) {
        const int row = wn * 64 + j * 16 + (lane & 15);
        const int g = ks * 4 + (lane >> 4);
        bfv[j] = *(const bf16x8*)&Bs[row * BK + (g ^ (row & 7)) * 8];
      }
#pragma unroll
      for (int i = 0; i < 4; ++i)
#pragma unroll
        for (int j = 0; j < 4; ++j)
          acc[i][j] = __builtin_amdgcn_mfma_f32_16x16x32_bf16(
              af[i], bfv[j], acc[i][j], 0, 0, 0);
    }
    __syncthreads();
  }

  const int ccol = lane & 15;
  const int crow = (lane >> 4) * 4;
#pragma unroll
  for (int i = 0; i < 4; ++i) {
#pragma unroll
    for (int j = 0; j < 4; ++j) {
      const int gcol = nblk + wn * 64 + j * 16 + ccol;
      const int growb = m0 + wm * 64 + i * 16 + crow;
#pragma unroll
      for (int r = 0; r < 4; ++r) {
        float v = acc[i][j][r];
        if constexpr (__is_same(OutT, bf16_t))
          C[(size_t)(growb + r) * ldc + gcol] = __float2bfloat16(v);
        else
          C[(size_t)(growb + r) * ldc + gcol] = v;
      }
    }
  }
}

// S[bh][d][e] += sum_m K[b,m,h,d] * V[b,m,h,e]  (fp32 atomics, m split 8-way)
__global__ __launch_bounds__(256)
void ktv_kernel(const bf16_t* __restrict__ qkv, float* __restrict__ S)
{
  __shared__ float Kf[32][64];
  __shared__ float Vf[32][64];
  const int bh = blockIdx.x;              // b*16 + h
  const int b = bh >> 4, hh = bh & 15;
  const int mc = blockIdx.y;              // 0..7 -> 256 rows each
  const int t = threadIdx.x;
  const int d0 = (t & 15) * 4;
  const int e0 = (t >> 4) * 4;

  const bf16_t* kbase = qkv + (size_t)b * 2048 * 3072 + 1024 + hh * 64;
  const bf16_t* vbase = kbase + 1024;

  float acc[4][4];
#pragma unroll
  for (int i = 0; i < 4; ++i)
#pragma unroll
    for (int j = 0; j < 4; ++j) acc[i][j] = 0.f;

  const int sr = t >> 3;          // 0..31
  const int sc = (t & 7) * 8;     // 0..56

  for (int m0 = mc * 256; m0 < mc * 256 + 256; m0 += 32) {
    uint4 ku = *(const uint4*)(kbase + (size_t)(m0 + sr) * 3072 + sc);
    uint4 vu = *(const uint4*)(vbase + (size_t)(m0 + sr) * 3072 + sc);
    __syncthreads();               // protect previous chunk's reads
    unpack8_bf16(&Kf[sr][sc], ku);
    unpack8_bf16(&Vf[sr][sc], vu);
    __syncthreads();
#pragma unroll
    for (int m = 0; m < 32; ++m) {
      float kv[4], vv[4];
#pragma unroll
      for (int i = 0; i < 4; ++i) kv[i] = Kf[m][d0 + i];
#pragma unroll
      for (int j = 0; j < 4; ++j) vv[j] = Vf[m][e0 + j];
#pragma unroll
      for (int i = 0; i < 4; ++i)
#pragma unroll
        for (int j = 0; j < 4; ++j) acc[i][j] += kv[i] * vv[j];
    }
  }
  float* Sp = S + (size_t)bh * 64 * 64;
#pragma unroll
  for (int i = 0; i < 4; ++i)
#pragma unroll
    for (int j = 0; j < 4; ++j)
      atomicAdd(&Sp[(d0 + i) * 64 + e0 + j], acc[i][j]);
}

// O[b,m,h,e] = sum_d Q[b,m,h,d] * S[bh][d][e]; O written into qkv's K-columns.
__global__ __launch_bounds__(256)
void qs_kernel(const bf16_t* __restrict__ qkv, const float* __restrict__ S,
               bf16_t* __restrict__ O)
{
  __shared__ float Ss[64][64];
  const int bh = blockIdx.x;
  const int b = bh >> 4, hh = bh & 15;
  const int mt = blockIdx.y;   // 0..15 -> 128 rows each
  const int t = threadIdx.x;

  const float* Sp = S + (size_t)bh * 4096;
  {
    float* sf = &Ss[0][0];
#pragma unroll
    for (int i = 0; i < 16; ++i) sf[t * 16 + i] = Sp[t * 16 + i];
  }
  __syncthreads();

  const int row = t >> 1;            // 0..127
  const int e0 = (t & 1) * 32;
  const int m = mt * 128 + row;
  const bf16_t* qp = qkv + (size_t)(b * 2048 + m) * 3072 + hh * 64;

  float acc[32];
#pragma unroll
  for (int e = 0; e < 32; ++e) acc[e] = 0.f;

  const uint4* qv = (const uint4*)qp;
#pragma unroll
  for (int c = 0; c < 8; ++c) {
    float qf[8];
    unpack8_bf16(qf, qv[c]);
#pragma unroll
    for (int p = 0; p < 8; ++p) {
      const int d = c * 8 + p;
      const float q = qf[p];
#pragma unroll
      for (int e = 0; e < 32; ++e) acc[e] += q * Ss[d][e0 + e];
    }
  }

  bf16_t* op = O + (size_t)(b * 2048 + m) * 3072 + hh * 64 + e0;
#pragma unroll
  for (int c = 0; c < 4; ++c) {
    uint4 u;
    unsigned* pu = (unsigned*)&u;
#pragma unroll
    for (int p = 0; p < 4; ++p) {
      const int e = c * 8 + p * 2;
      unsigned lo = bf16_bits(acc[e]);
      unsigned hi = bf16_bits(acc[e + 1]);
      pu[p] = lo | (hi << 16);
    }
    ((uint4*)op)[c] = u;
  }
}

extern "C" void kernel_launch(void* const* d_in, const int* in_sizes, int n_in,
                              void* d_out, int out_size, void* d_ws, size_t ws_size,
                              hipStream_t stream)
{
  const float* h  = (const float*)d_in[0];
  const float* Wq = (const float*)d_in[1];
  const float* Wk = (const float*)d_in[2];
  const float* Wv = (const float*)d_in[3];
  // d_in[4] = Wspan: dead code in reference
  const float* Wo = (const float*)d_in[5];
  float* out = (float*)d_out;

  char* ws = (char*)d_ws;
  bf16_t* hb  = (bf16_t*)(ws);                              // [4096,1024] bf16, 8 MB
  bf16_t* Wqb = (bf16_t*)(ws + (8u << 20));                 // 2 MB each
  bf16_t* Wkb = (bf16_t*)(ws + (10u << 20));
  bf16_t* Wvb = (bf16_t*)(ws + (12u << 20));
  bf16_t* Wob = (bf16_t*)(ws + (14u << 20));
  bf16_t* qkv = (bf16_t*)(ws + (16u << 20));                // [4096,3072] bf16, 24 MB
  float*  S   = (float*) (ws + (40u << 20));                // [32,64,64] fp32

  hipMemsetAsync(S, 0, 32 * 64 * 64 * sizeof(float), stream);

  // fp32 -> bf16 conversions
  cvt_one<<<dim3(4096), 256, 0, stream>>>(h, hb);
  cvt_w4<<<dim3(1024, 4), 256, 0, stream>>>(Wq, Wk, Wv, Wo, Wqb, Wkb, Wvb, Wob);

  // qkv[:, 0:1024]=Q, [:,1024:2048]=K, [:,2048:3072]=V
  gemm_nt<bf16_t><<<dim3(32, 24), 256, 0, stream>>>(hb, 1024, Wqb, Wkb, Wvb, qkv, 3072, 1024);
  ktv_kernel<<<dim3(32, 8), 256, 0, stream>>>(qkv, S);
  // O overwrites the (now dead) K columns of qkv
  qs_kernel<<<dim3(32, 16), 256, 0, stream>>>(qkv, S, qkv + 1024);
  gemm_nt<float><<<dim3(32, 8), 256, 0, stream>>>(qkv + 1024, 3072, Wob, Wob, Wob, out, 1024, 1024);
}